// Round 6
// baseline (201.875 us; speedup 1.0000x reference)
//
#include <hip/hip_runtime.h>

#define B_ROWS 16384
#define K_DIM  128
#define C_CLS  32

// ws layout (bytes)
#define O_COUNTS   0               // 32 int
#define O_FIRST    256             // 32 int
#define O_RANK     512             // 32 int
#define O_KLACC    1024            // 1 float
#define O_LD2      1152            // 32 float
#define O_COLSUM   2048            // 32*128*4 = 16384
#define O_MU       18432           // 16384
#define O_S        102400          // 32*16384*4 = 2 MiB
#define O_PART     (102400 + 2097152)      // 128 blocks * 64 KiB = 8 MiB
#define O_INV      O_PART          // aliased: partials die at k_finalize,
                                   // INV is produced by k_sweep afterwards

// ---------------------------------------------------------------------------
// K0: init the small header (ws is poisoned 0xAA before every launch).
// ---------------------------------------------------------------------------
__global__ __launch_bounds__(256) void k_init(int* __restrict__ counts,
    int* __restrict__ first, float* __restrict__ colsum, float* __restrict__ klacc) {
  const int t = threadIdx.x;
  if (t < C_CLS) { counts[t] = 0; first[t] = 0x7fffffff; }
  if (t == 0) klacc[0] = 0.f;
  for (int i = t; i < C_CLS * K_DIM; i += 256) colsum[i] = 0.f;
}

// ---------------------------------------------------------------------------
// K2: per-class partial second moments, self-service row discovery (r6: the
// former k_bucket single-block kernel with 48K contended LDS atomics is
// gone). Block (c,s) scans label chunk [s*4096,(s+1)*4096), ballot-compacts
// matching rows into an LDS list (capacity 4096 = exact worst case), then
// runs the 8x8-register-tile Gram accumulation over 32-row batches.
// Non-atomic 64KB partial write (r4 fix); counts/first via 4-way global
// atomics per class; colsum via per-column atomics (16K total).
// ---------------------------------------------------------------------------
__global__ __launch_bounds__(256) void k_scatter(const float* __restrict__ feat,
    const int* __restrict__ label, int* __restrict__ counts, int* __restrict__ first,
    float* __restrict__ part, float* __restrict__ colsum) {
  const int c = blockIdx.x >> 2, s = blockIdx.x & 3;
  __shared__ int lls[4096];
  __shared__ int lcnt;
  __shared__ __align__(16) float ls[32 * 128];
  const int t = threadIdx.x;
  if (t == 0) lcnt = 0;
  __syncthreads();
  // ---- compaction scan of this chunk ----
  int myMin = 0x7fffffff;
  const int lane = t & 63;
  for (int r0 = 0; r0 < 4096; r0 += 256) {
    const int i = s * 4096 + r0 + t;
    const bool match = (label[i] == c);
    unsigned long long mask = __ballot(match);
    int prefix = __popcll(mask & ((1ull << lane) - 1ull));
    int wcnt = __popcll(mask);
    int base = 0;
    if (lane == 0 && wcnt) base = atomicAdd(&lcnt, wcnt);
    base = __shfl(base, 0);
    if (match) { lls[base + prefix] = i; myMin = min(myMin, i); }
  }
  #pragma unroll
  for (int off = 32; off > 0; off >>= 1) myMin = min(myMin, __shfl_xor(myMin, off));
  if (lane == 0 && myMin != 0x7fffffff) atomicMin(&first[c], myMin);
  __syncthreads();
  const int n = lcnt;
  if (t == 0) atomicAdd(&counts[c], n);

  // ---- Gram accumulation ----
  const int tr = t >> 4, tc = t & 15;
  float acc[8][8];
  #pragma unroll
  for (int i = 0; i < 8; ++i)
    #pragma unroll
    for (int j = 0; j < 8; ++j) acc[i][j] = 0.f;
  float cs = 0.f;
  const int col = t & 127, half = t >> 7;
  for (int base2 = 0; base2 < n; base2 += 32) {
    const int nb = min(32, n - base2);
    __syncthreads();             // protect ls against previous-iter readers
    #pragma unroll
    for (int w = 0; w < 4; ++w) {
      int f4 = w * 256 + t;      // 0..1023 over 32 rows x 32 float4
      int r = f4 >> 5, c4 = f4 & 31;
      float4 v = make_float4(0.f, 0.f, 0.f, 0.f);
      if (r < nb) {
        int row = lls[base2 + r];
        v = ((const float4*)(feat + (long)row * K_DIM))[c4];
      }
      ((float4*)ls)[f4] = v;     // zero-padded tail rows contribute nothing
    }
    __syncthreads();
    #pragma unroll
    for (int r0 = 0; r0 < 16; ++r0) cs += ls[(half * 16 + r0) * 128 + col];
    for (int r = 0; r < nb; ++r) {
      const float4* lr = (const float4*)(ls + r * 128);
      float4 A0 = lr[tr * 2], A1 = lr[tr * 2 + 1];
      float4 B0 = lr[tc * 2], B1 = lr[tc * 2 + 1];
      float av[8] = {A0.x, A0.y, A0.z, A0.w, A1.x, A1.y, A1.z, A1.w};
      float bv[8] = {B0.x, B0.y, B0.z, B0.w, B1.x, B1.y, B1.z, B1.w};
      #pragma unroll
      for (int i = 0; i < 8; ++i)
        #pragma unroll
        for (int j = 0; j < 8; ++j) acc[i][j] += av[i] * bv[j];
    }
  }
  // non-atomic partial write, vectorized
  float* Pc = part + (long)blockIdx.x * 16384;
  #pragma unroll
  for (int i = 0; i < 8; ++i) {
    float4* prow = (float4*)(Pc + (tr * 8 + i) * 128);
    prow[tc * 2]     = make_float4(acc[i][0], acc[i][1], acc[i][2], acc[i][3]);
    prow[tc * 2 + 1] = make_float4(acc[i][4], acc[i][5], acc[i][6], acc[i][7]);
  }
  atomicAdd(&colsum[c * 128 + col], cs);
}

// ---------------------------------------------------------------------------
// K3: mu = colsum/n ; S = (sum of 4 partials)/n - mu mu^T + I ; rank[c].
// ---------------------------------------------------------------------------
__global__ __launch_bounds__(256) void k_finalize(const float* __restrict__ part,
    float* __restrict__ S, const float* __restrict__ colsum,
    const int* __restrict__ counts, const int* __restrict__ first,
    float* __restrict__ mu, int* __restrict__ rank_g) {
  const int c = blockIdx.x, t = threadIdx.x;
  __shared__ __align__(16) float ml[128];
  const float n = (float)counts[c];
  if (t < 128) {
    float m = colsum[c * 128 + t] / n;
    ml[t] = m;
    mu[c * 128 + t] = m;
  }
  if (t == 0) {
    const int f = first[c];
    int r = 0;
    for (int c2 = 0; c2 < C_CLS; ++c2) {
      const int f2 = first[c2];
      r += (f2 < f) || (f2 == f && c2 < c);
    }
    rank_g[c] = r;
  }
  __syncthreads();
  const float4* P0 = (const float4*)(part + (long)(c * 4 + 0) * 16384);
  const float4* P1 = (const float4*)(part + (long)(c * 4 + 1) * 16384);
  const float4* P2 = (const float4*)(part + (long)(c * 4 + 2) * 16384);
  const float4* P3 = (const float4*)(part + (long)(c * 4 + 3) * 16384);
  float4* S4 = (float4*)(S + c * 16384);
  const float rn = 1.0f / n;
  #pragma unroll
  for (int q = 0; q < 16; ++q) {
    int f4 = q * 256 + t;
    int a = f4 >> 5, b = (f4 & 31) * 4;
    float4 v0 = P0[f4], v1 = P1[f4], v2 = P2[f4], v3 = P3[f4];
    float4 v;
    v.x = (v0.x + v1.x) + (v2.x + v3.x);
    v.y = (v0.y + v1.y) + (v2.y + v3.y);
    v.z = (v0.z + v1.z) + (v2.z + v3.z);
    v.w = (v0.w + v1.w) + (v2.w + v3.w);
    float ma = ml[a];
    v.x = v.x * rn - ma * ml[b + 0] + ((a == b + 0) ? 1.f : 0.f);
    v.y = v.y * rn - ma * ml[b + 1] + ((a == b + 1) ? 1.f : 0.f);
    v.z = v.z * rn - ma * ml[b + 2] + ((a == b + 2) ? 1.f : 0.f);
    v.w = v.w * rn - ma * ml[b + 3] + ((a == b + 3) ? 1.f : 0.f);
    S4[f4] = v;
  }
}

// ---------------------------------------------------------------------------
// K4: BLOCKED sweep-operator inversion + log2-det (r6: 55us version was
// barrier/latency-bound at 1030 cy/step x 128 steps, VALUBusy 3.8%; blocking
// 4 pivots/phase cuts sync points 128 -> 32 at ~2x the arithmetic).
//
// Layout: 512 threads; thread t holds rows rq = 16q + h (h = t>>5, q=0..7),
// float4-cols [4*(t&31) .. +3] -> A[8] = 32 VGPRs. Matrix stays symmetric
// throughout (sweep preserves symmetry), so the 4-row pivot panel R in LDS
// also provides the pivot COLUMNS (Crow[u] = R[u][rq]).
//
// Per phase (pivots J = {4P..4P+3}):
//   1. owners export panel R = A[J][:] (4x128) to LDS (double-buffered)
//   2. barrier (the only one per phase)
//   3. every thread redundantly mini-sweeps the 4x4 block D -> m = -D^{-1}
//      (registers, static indices), accumulating log2 pivots
//   4. E[u] = sum_v D^{-1}[u][v] * R[v][cols]  (per-thread, 4 float4)
//   5. Schur: A[q] -= sum_u Crow[u]*E[u]; col-panel lanes (c4i==P) overwrite
//      with sum_v Crow[v]*D^{-1}[v][u]; owner rows overwrite with E (or m-row
//      on the diag block). All exact -> INV = -A at the end, no fixups.
// ---------------------------------------------------------------------------
__global__ __launch_bounds__(512) void k_sweep(const float* __restrict__ S,
    float* __restrict__ INVg, float* __restrict__ ld2) {
  const int c = blockIdx.x, t = threadIdx.x;
  __shared__ __align__(16) float pan[2][4][128];
  const float4* S4 = (const float4*)(S + c * 16384);
  float4 A[8];
  #pragma unroll
  for (int q = 0; q < 8; ++q) A[q] = S4[q * 512 + t];
  const int h = t >> 5, c4i = t & 31;
  float lda = 0.f;

  for (int P = 0; P < 32; ++P) {
    float (*Rp)[128] = pan[P & 1];
    const int qexp = P >> 2;          // rows 4P..4P+3 share q = P>>2
    const int hbase = (4 * P) & 15;
    const int u0 = h - hbase;
    // ---- export 4-row panel ----
    if ((unsigned)u0 < 4u) {
      float4 ex = A[0];
      #pragma unroll
      for (int q = 1; q < 8; ++q) if (q == qexp) ex = A[q];  // static select
      ((float4*)Rp[u0])[c4i] = ex;
    }
    __syncthreads();
    // ---- redundant 4x4 mini-sweep: m := sweep(D) = -D^{-1} ----
    float m[4][4];
    #pragma unroll
    for (int u = 0; u < 4; ++u) {
      float4 dr = ((const float4*)Rp[u])[P];   // broadcast read
      m[u][0] = dr.x; m[u][1] = dr.y; m[u][2] = dr.z; m[u][3] = dr.w;
    }
    #pragma unroll
    for (int p = 0; p < 4; ++p) {
      const float d = m[p][p];
      const float dinv = 1.0f / d;
      lda += __log2f(d);
      #pragma unroll
      for (int r = 0; r < 4; ++r) {
        if (r != p) {
          #pragma unroll
          for (int cc = 0; cc < 4; ++cc)
            if (cc != p) m[r][cc] -= m[r][p] * m[p][cc] * dinv;
        }
      }
      #pragma unroll
      for (int cc = 0; cc < 4; ++cc) if (cc != p) m[p][cc] *= dinv;
      #pragma unroll
      for (int r = 0; r < 4; ++r) if (r != p) m[r][p] *= dinv;
      m[p][p] = -dinv;
    }
    // ---- E[u] = sum_v D^{-1}[u][v] * R[v][mycols]   (D^{-1} = -m) ----
    float4 Rv[4], E[4];
    #pragma unroll
    for (int v = 0; v < 4; ++v) Rv[v] = ((const float4*)Rp[v])[c4i];
    #pragma unroll
    for (int u = 0; u < 4; ++u) {
      float4 e = make_float4(0.f, 0.f, 0.f, 0.f);
      #pragma unroll
      for (int v = 0; v < 4; ++v) {
        const float dv = -m[u][v];
        e.x += dv * Rv[v].x; e.y += dv * Rv[v].y;
        e.z += dv * Rv[v].z; e.w += dv * Rv[v].w;
      }
      E[u] = e;
    }
    // ---- rank-4 Schur update + panel-column overwrite ----
    const bool colp = (c4i == P);
    #pragma unroll
    for (int q = 0; q < 8; ++q) {
      const int rq = q * 16 + h;
      const float cr0 = Rp[0][rq], cr1 = Rp[1][rq];
      const float cr2 = Rp[2][rq], cr3 = Rp[3][rq];
      float4 a = A[q];
      a.x -= cr0 * E[0].x + cr1 * E[1].x + cr2 * E[2].x + cr3 * E[3].x;
      a.y -= cr0 * E[0].y + cr1 * E[1].y + cr2 * E[2].y + cr3 * E[3].y;
      a.z -= cr0 * E[0].z + cr1 * E[1].z + cr2 * E[2].z + cr3 * E[3].z;
      a.w -= cr0 * E[0].w + cr1 * E[1].w + cr2 * E[2].w + cr3 * E[3].w;
      if (colp) {  // cols 4P..4P+3: M[:,J] = A_old[:,J] * D^{-1} = Crow * (-m)
        a.x = -(cr0 * m[0][0] + cr1 * m[1][0] + cr2 * m[2][0] + cr3 * m[3][0]);
        a.y = -(cr0 * m[0][1] + cr1 * m[1][1] + cr2 * m[2][1] + cr3 * m[3][1]);
        a.z = -(cr0 * m[0][2] + cr1 * m[1][2] + cr2 * m[2][2] + cr3 * m[3][2]);
        a.w = -(cr0 * m[0][3] + cr1 * m[1][3] + cr2 * m[2][3] + cr3 * m[3][3]);
      }
      A[q] = a;
    }
    // ---- panel-row overwrite: M[J][:] = E ; diag block = -D^{-1} = m ----
    if ((unsigned)u0 < 4u) {
      float4 ev = E[0];
      #pragma unroll
      for (int u = 1; u < 4; ++u) if (u == u0) ev = E[u];
      if (colp) {
        ev = make_float4(m[0][0], m[0][1], m[0][2], m[0][3]);
        #pragma unroll
        for (int u = 1; u < 4; ++u)
          if (u == u0) ev = make_float4(m[u][0], m[u][1], m[u][2], m[u][3]);
      }
      #pragma unroll
      for (int q = 0; q < 8; ++q) if (q == qexp) A[q] = ev;
    }
  }

  // full sweep of SPD S gives -S^{-1}; write INV = -A (exact, no fixups)
  float4* O4 = (float4*)(INVg + c * 16384);
  #pragma unroll
  for (int q = 0; q < 8; ++q)
    O4[q * 512 + t] = make_float4(-A[q].x, -A[q].y, -A[q].z, -A[q].w);
  if (t == 0) ld2[c] = lda;          // v_log_f32 is log2 = slogdet/ln2
}

// ---------------------------------------------------------------------------
// K5: pairwise tr+quad fused: sum_f inv_j[f] * (S_i[f] + diff[a]*diff[b]);
// kl = 0.5*(ld2[j]-ld2[i] - 128 + sum); masked atomic accumulate.
// ---------------------------------------------------------------------------
__global__ __launch_bounds__(256) void k_pairs(const float* __restrict__ S,
    const float* __restrict__ INVg, const float* __restrict__ mu,
    const float* __restrict__ ld2, const int* __restrict__ rank_g,
    float* __restrict__ klacc) {
  const int j = blockIdx.x, i = blockIdx.y;
  if (rank_g[i] > C_CLS - 2 || rank_g[j] < 1) return;
  __shared__ __align__(16) float dl[128];
  __shared__ float wsum[4];
  const int t = threadIdx.x;
  if (t < 128) dl[t] = mu[i * 128 + t] - mu[j * 128 + t];
  __syncthreads();
  const float4* Si4 = (const float4*)(S + i * 16384);
  const float4* Ij4 = (const float4*)(INVg + j * 16384);
  float s = 0.f;
  #pragma unroll
  for (int q = 0; q < 16; ++q) {
    int f4 = q * 256 + t;
    int a = f4 >> 5, b4 = f4 & 31;
    float da = dl[a];
    float4 db = ((const float4*)dl)[b4];
    float4 si = Si4[f4], ij = Ij4[f4];
    s += ij.x * (si.x + da * db.x);
    s += ij.y * (si.y + da * db.y);
    s += ij.z * (si.z + da * db.z);
    s += ij.w * (si.w + da * db.w);
  }
  #pragma unroll
  for (int off = 32; off > 0; off >>= 1) s += __shfl_xor(s, off);
  if ((t & 63) == 0) wsum[t >> 6] = s;
  __syncthreads();
  if (t == 0) {
    float tot = wsum[0] + wsum[1] + wsum[2] + wsum[3];
    float kl = 0.5f * ((ld2[j] - ld2[i]) - 128.0f + tot);
    atomicAdd(klacc, kl);
  }
}

// ---------------------------------------------------------------------------
// K6: out = klacc - sum(mu^2)
// ---------------------------------------------------------------------------
__global__ __launch_bounds__(256) void k_final(const float* __restrict__ mu,
    const float* __restrict__ klacc, float* __restrict__ out) {
  const int t = threadIdx.x;
  __shared__ float wsum[4];
  float s = 0.f;
  #pragma unroll
  for (int q = 0; q < 16; ++q) {
    float m = mu[q * 256 + t];
    s += m * m;
  }
  #pragma unroll
  for (int off = 32; off > 0; off >>= 1) s += __shfl_xor(s, off);
  if ((t & 63) == 0) wsum[t >> 6] = s;
  __syncthreads();
  if (t == 0) out[0] = klacc[0] - (wsum[0] + wsum[1] + wsum[2] + wsum[3]);
}

extern "C" void kernel_launch(void* const* d_in, const int* in_sizes, int n_in,
                              void* d_out, int out_size, void* d_ws, size_t ws_size,
                              hipStream_t stream) {
  const float* feat  = (const float*)d_in[0];
  const int*   label = (const int*)d_in[1];
  // d_in[2] (pan) is unused by the reference module.
  float* out = (float*)d_out;
  char*  ws  = (char*)d_ws;

  int*   counts  = (int*)(ws + O_COUNTS);
  int*   first   = (int*)(ws + O_FIRST);
  int*   rank_g  = (int*)(ws + O_RANK);
  float* klacc   = (float*)(ws + O_KLACC);
  float* ld2     = (float*)(ws + O_LD2);
  float* colsum  = (float*)(ws + O_COLSUM);
  float* mu      = (float*)(ws + O_MU);
  float* S       = (float*)(ws + O_S);
  float* part    = (float*)(ws + O_PART);
  float* INVg    = (float*)(ws + O_INV);   // aliases part (sequenced after)

  k_init    <<<1,             256, 0, stream>>>(counts, first, colsum, klacc);
  k_scatter <<<128,           256, 0, stream>>>(feat, label, counts, first, part, colsum);
  k_finalize<<<C_CLS,         256, 0, stream>>>(part, S, colsum, counts, first, mu, rank_g);
  k_sweep   <<<C_CLS,         512, 0, stream>>>(S, INVg, ld2);
  k_pairs   <<<dim3(C_CLS, C_CLS), 256, 0, stream>>>(S, INVg, mu, ld2, rank_g, klacc);
  k_final   <<<1,             256, 0, stream>>>(mu, klacc, out);
}

// Round 7
// 159.617 us; speedup vs baseline: 1.2647x; 1.2647x over previous
//
#include <hip/hip_runtime.h>

#define B_ROWS 16384
#define K_DIM  128
#define C_CLS  32

// ws layout (bytes)
#define O_COUNTS   0               // 32 int
#define O_FIRST    256             // 32 int
#define O_RANK     512             // 32 int
#define O_LD2      1152            // 32 float
#define O_COLSUM   2048            // 32*128*4 = 16384
#define O_MU       18432           // 16384
#define O_S        102400          // 2 MiB
#define O_PART     (102400 + 2097152)   // NSPLIT*32 * 64 KiB partial slabs
#define O_INV      O_PART          // aliased: partials die inside k_sweepf
                                   // (read before INV is written at the end)

// ---------------------------------------------------------------------------
// K0: init header + output (ws/d_out are poisoned 0xAA before every launch).
// ---------------------------------------------------------------------------
__global__ __launch_bounds__(256) void k_init(int* __restrict__ counts,
    int* __restrict__ first, float* __restrict__ colsum, float* __restrict__ out) {
  const int t = threadIdx.x;
  if (t < C_CLS) { counts[t] = 0; first[t] = 0x7fffffff; }
  if (t == 0) out[0] = 0.f;
  for (int i = t; i < C_CLS * K_DIM; i += 256) colsum[i] = 0.f;
}

// ---------------------------------------------------------------------------
// K2: per-class partial second moments. NSPLIT splits/class (template: 8 if
// ws allows 16 MB of partials -> 256 blocks = every CU busy; else 4).
// Block (c,s) ballot-compacts its label chunk into an LDS row list, then
// 8x8-register-tile Gram over 32-row LDS-staged batches. Non-atomic 64 KB
// partial write; counts/first/colsum via cheap global atomics.
// ---------------------------------------------------------------------------
template<int NSPLIT>
__global__ __launch_bounds__(256) void k_scatter(const float* __restrict__ feat,
    const int* __restrict__ label, int* __restrict__ counts, int* __restrict__ first,
    float* __restrict__ part, float* __restrict__ colsum) {
  constexpr int CH = B_ROWS / NSPLIT;
  const int c = blockIdx.x / NSPLIT, s = blockIdx.x % NSPLIT;
  __shared__ int lls[CH];
  __shared__ int lcnt;
  __shared__ __align__(16) float ls[32 * 128];
  const int t = threadIdx.x;
  if (t == 0) lcnt = 0;
  __syncthreads();
  // ---- compaction scan of this chunk ----
  int myMin = 0x7fffffff;
  const int lane = t & 63;
  for (int r0 = 0; r0 < CH; r0 += 256) {
    const int i = s * CH + r0 + t;
    const bool match = (label[i] == c);
    unsigned long long mask = __ballot(match);
    int prefix = __popcll(mask & ((1ull << lane) - 1ull));
    int wcnt = __popcll(mask);
    int base = 0;
    if (lane == 0 && wcnt) base = atomicAdd(&lcnt, wcnt);
    base = __shfl(base, 0);
    if (match) { lls[base + prefix] = i; myMin = min(myMin, i); }
  }
  #pragma unroll
  for (int off = 32; off > 0; off >>= 1) myMin = min(myMin, __shfl_xor(myMin, off));
  if (lane == 0 && myMin != 0x7fffffff) atomicMin(&first[c], myMin);
  __syncthreads();
  const int n = lcnt;
  if (t == 0) atomicAdd(&counts[c], n);

  // ---- Gram accumulation ----
  const int tr = t >> 4, tc = t & 15;
  float acc[8][8];
  #pragma unroll
  for (int i = 0; i < 8; ++i)
    #pragma unroll
    for (int j = 0; j < 8; ++j) acc[i][j] = 0.f;
  float cs = 0.f;
  const int col = t & 127, half = t >> 7;
  for (int base2 = 0; base2 < n; base2 += 32) {
    const int nb = min(32, n - base2);
    __syncthreads();             // protect ls against previous-iter readers
    #pragma unroll
    for (int w = 0; w < 4; ++w) {
      int f4 = w * 256 + t;      // 0..1023 over 32 rows x 32 float4
      int r = f4 >> 5, c4 = f4 & 31;
      float4 v = make_float4(0.f, 0.f, 0.f, 0.f);
      if (r < nb) {
        int row = lls[base2 + r];
        v = ((const float4*)(feat + (long)row * K_DIM))[c4];
      }
      ((float4*)ls)[f4] = v;     // zero-padded tail rows contribute nothing
    }
    __syncthreads();
    #pragma unroll
    for (int r0 = 0; r0 < 16; ++r0) cs += ls[(half * 16 + r0) * 128 + col];
    for (int r = 0; r < nb; ++r) {
      const float4* lr = (const float4*)(ls + r * 128);
      float4 A0 = lr[tr * 2], A1 = lr[tr * 2 + 1];
      float4 B0 = lr[tc * 2], B1 = lr[tc * 2 + 1];
      float av[8] = {A0.x, A0.y, A0.z, A0.w, A1.x, A1.y, A1.z, A1.w};
      float bv[8] = {B0.x, B0.y, B0.z, B0.w, B1.x, B1.y, B1.z, B1.w};
      #pragma unroll
      for (int i = 0; i < 8; ++i)
        #pragma unroll
        for (int j = 0; j < 8; ++j) acc[i][j] += av[i] * bv[j];
    }
  }
  float* Pc = part + (long)blockIdx.x * 16384;
  #pragma unroll
  for (int i = 0; i < 8; ++i) {
    float4* prow = (float4*)(Pc + (tr * 8 + i) * 128);
    prow[tc * 2]     = make_float4(acc[i][0], acc[i][1], acc[i][2], acc[i][3]);
    prow[tc * 2 + 1] = make_float4(acc[i][4], acc[i][5], acc[i][6], acc[i][7]);
  }
  atomicAdd(&colsum[c * 128 + col], cs);
}

// ---------------------------------------------------------------------------
// K4: FUSED finalize + rolled sweep-operator inversion + log2-det.
// r7 retile: 1024 threads (4 waves/SIMD, was 2) -> double the latency hiding
// for the per-step LDS-broadcast chain that r5/r6 showed is the real cost
// (r6 post-mortem: barriers were NOT dominant; NB=4 blocking tripled VALU).
// Math is r5's verified NB=1 parked-diag sweep, A[4] float4/thread,
// rows rq = 32q + h (h = t>>5), float4-col c4i = t&31.
//
// Inline finalize: A[q] = (sum of NSPLIT partials)*rn - mu mu^T + I, written
// to S (k_pairs needs it), mu/rank written here too.
//
// Parked-diag trick: exporter writes pivot row with vbuf[P] := d-1, raw d in
// slot 128; the generic update A -= vr*(vc*dinv) is then exact for row and
// col P; only diag[P][P] is off by exactly +2 (introduced once, additive,
// never re-read) -> fixed in the final write: INV = -A + 2*[diag].
// ---------------------------------------------------------------------------
template<int NSPLIT>
__global__ __launch_bounds__(1024) void k_sweepf(const float* __restrict__ part,
    const float* __restrict__ colsum, const int* __restrict__ counts,
    const int* __restrict__ first, float* __restrict__ S, float* __restrict__ INVg,
    float* __restrict__ mu, int* __restrict__ rank_g, float* __restrict__ ld2) {
  const int c = blockIdx.x, t = threadIdx.x;
  __shared__ __align__(16) float ml[128];
  __shared__ __align__(16) float vbuf[2][132];   // slot [128] carries d
  const float n = (float)counts[c];
  const float rn = 1.0f / n;
  if (t < 128) {
    float m = colsum[c * 128 + t] * rn;
    ml[t] = m;
    mu[c * 128 + t] = m;
  }
  if (t == 0) {
    const int f = first[c];
    int r = 0;
    for (int c2 = 0; c2 < C_CLS; ++c2) {
      const int f2 = first[c2];
      r += (f2 < f) || (f2 == f && c2 < c);
    }
    rank_g[c] = r;
  }
  __syncthreads();
  const int h = t >> 5, c4i = t & 31;
  float4 A[4];
  float4* S4 = (float4*)(S + c * 16384);
  #pragma unroll
  for (int q = 0; q < 4; ++q) {
    const int f4 = q * 1024 + t;
    float4 v = make_float4(0.f, 0.f, 0.f, 0.f);
    #pragma unroll
    for (int k = 0; k < NSPLIT; ++k) {
      const float4 p = ((const float4*)(part + (long)(c * NSPLIT + k) * 16384))[f4];
      v.x += p.x; v.y += p.y; v.z += p.z; v.w += p.w;
    }
    const int row = q * 32 + h;
    const float mr = ml[row];
    const float4 mc = ((const float4*)ml)[c4i];
    const int b = 4 * c4i;
    v.x = v.x * rn - mr * mc.x + ((row == b + 0) ? 1.f : 0.f);
    v.y = v.y * rn - mr * mc.y + ((row == b + 1) ? 1.f : 0.f);
    v.z = v.z * rn - mr * mc.z + ((row == b + 2) ? 1.f : 0.f);
    v.w = v.w * rn - mr * mc.w + ((row == b + 3) ? 1.f : 0.f);
    A[q] = v;
    S4[f4] = v;
  }
  float lda = 0.f;
  for (int P = 0; P < 128; ++P) {
    float* vb = vbuf[P & 1];
    // ---- export row P (threads with h == P&31), with in-LDS fixup ----
    if (h == (P & 31)) {
      const int qexp = P >> 5;
      float4 ex = A[0];
      #pragma unroll
      for (int q = 1; q < 4; ++q) if (q == qexp) ex = A[q];   // static select
      if (c4i == (P >> 2)) {                 // this float4 holds col P (diag d)
        const int e = P & 3;
        float dv = (e == 0) ? ex.x : (e == 1) ? ex.y : (e == 2) ? ex.z : ex.w;
        vb[128] = dv;                        // broadcast raw d
        if (e == 0) ex.x -= 1.f; else if (e == 1) ex.y -= 1.f;
        else if (e == 2) ex.z -= 1.f; else ex.w -= 1.f;       // vbuf[P] = d-1
      }
      ((float4*)vb)[c4i] = ex;
    }
    __syncthreads();
    // ---- generic rank-1 update, zero predication ----
    const float d = vb[128];
    const float dinv = 1.0f / d;
    lda += __log2f(d);
    const float4 vc = ((const float4*)vb)[c4i];
    const float4 wc = make_float4(vc.x * dinv, vc.y * dinv, vc.z * dinv, vc.w * dinv);
    #pragma unroll
    for (int q = 0; q < 4; ++q) {
      const float vr = vb[q * 32 + h];       // row-P lane reads d-1 automatically
      A[q].x -= vr * wc.x;
      A[q].y -= vr * wc.y;
      A[q].z -= vr * wc.z;
      A[q].w -= vr * wc.w;
    }
    // double-buffered vbuf: writes to buf[(P+2)&1] are separated from step-P
    // reads by step-(P+1)'s barrier.
  }
  // ---- write INV = -A, lazily fixing the +2 diag error ----
  float4* O4 = (float4*)(INVg + c * 16384);
  const int e = h & 3;                        // diag element position = rq & 3
  #pragma unroll
  for (int q = 0; q < 4; ++q) {
    const int rq = q * 32 + h;
    const float pf = (c4i == (rq >> 2)) ? 2.f : 0.f;
    float4 o;
    o.x = ((e == 0) ? pf : 0.f) - A[q].x;
    o.y = ((e == 1) ? pf : 0.f) - A[q].y;
    o.z = ((e == 2) ? pf : 0.f) - A[q].z;
    o.w = ((e == 3) ? pf : 0.f) - A[q].w;
    O4[q * 1024 + t] = o;
  }
  if (t == 0) ld2[c] = lda;          // v_log_f32 is log2 = slogdet/ln2
}

// ---------------------------------------------------------------------------
// K5: pairwise tr+quad fused + (block 0,0) the -sum(mu^2) term; accumulates
// straight into d_out (zeroed by k_init). kl = 0.5*(ld2j-ld2i-128+sum).
// ---------------------------------------------------------------------------
__global__ __launch_bounds__(256) void k_pairs(const float* __restrict__ S,
    const float* __restrict__ INVg, const float* __restrict__ mu,
    const float* __restrict__ ld2, const int* __restrict__ rank_g,
    float* __restrict__ out) {
  const int j = blockIdx.x, i = blockIdx.y;
  const int t = threadIdx.x;
  __shared__ __align__(16) float dl[128];
  __shared__ float wsum[4];
  if (i == 0 && j == 0) {            // block-uniform: fused -sum(mu^2)
    float s2 = 0.f;
    #pragma unroll
    for (int q = 0; q < 16; ++q) { float m = mu[q * 256 + t]; s2 += m * m; }
    #pragma unroll
    for (int off = 32; off > 0; off >>= 1) s2 += __shfl_xor(s2, off);
    if ((t & 63) == 0) wsum[t >> 6] = s2;
    __syncthreads();
    if (t == 0) atomicAdd(out, -(wsum[0] + wsum[1] + wsum[2] + wsum[3]));
    __syncthreads();                 // wsum reused below
  }
  if (rank_g[i] > C_CLS - 2 || rank_g[j] < 1) return;
  if (t < 128) dl[t] = mu[i * 128 + t] - mu[j * 128 + t];
  __syncthreads();
  const float4* Si4 = (const float4*)(S + i * 16384);
  const float4* Ij4 = (const float4*)(INVg + j * 16384);
  float s = 0.f;
  #pragma unroll
  for (int q = 0; q < 16; ++q) {
    int f4 = q * 256 + t;
    int a = f4 >> 5, b4 = f4 & 31;
    float da = dl[a];
    float4 db = ((const float4*)dl)[b4];
    float4 si = Si4[f4], ij = Ij4[f4];
    s += ij.x * (si.x + da * db.x);
    s += ij.y * (si.y + da * db.y);
    s += ij.z * (si.z + da * db.z);
    s += ij.w * (si.w + da * db.w);
  }
  #pragma unroll
  for (int off = 32; off > 0; off >>= 1) s += __shfl_xor(s, off);
  if ((t & 63) == 0) wsum[t >> 6] = s;
  __syncthreads();
  if (t == 0) {
    float tot = wsum[0] + wsum[1] + wsum[2] + wsum[3];
    float kl = 0.5f * ((ld2[j] - ld2[i]) - 128.0f + tot);
    atomicAdd(out, kl);
  }
}

extern "C" void kernel_launch(void* const* d_in, const int* in_sizes, int n_in,
                              void* d_out, int out_size, void* d_ws, size_t ws_size,
                              hipStream_t stream) {
  const float* feat  = (const float*)d_in[0];
  const int*   label = (const int*)d_in[1];
  // d_in[2] (pan) is unused by the reference module.
  float* out = (float*)d_out;
  char*  ws  = (char*)d_ws;

  int*   counts  = (int*)(ws + O_COUNTS);
  int*   first   = (int*)(ws + O_FIRST);
  int*   rank_g  = (int*)(ws + O_RANK);
  float* ld2     = (float*)(ws + O_LD2);
  float* colsum  = (float*)(ws + O_COLSUM);
  float* mu      = (float*)(ws + O_MU);
  float* S       = (float*)(ws + O_S);
  float* part    = (float*)(ws + O_PART);
  float* INVg    = (float*)(ws + O_INV);   // aliases part (read-then-write order)

  const size_t need8 = (size_t)O_PART + (size_t)C_CLS * 8 * 65536;  // ~19 MB

  k_init<<<1, 256, 0, stream>>>(counts, first, colsum, out);
  if (ws_size >= need8) {
    k_scatter<8><<<C_CLS * 8, 256,  0, stream>>>(feat, label, counts, first, part, colsum);
    k_sweepf<8> <<<C_CLS,     1024, 0, stream>>>(part, colsum, counts, first, S, INVg, mu, rank_g, ld2);
  } else {
    k_scatter<4><<<C_CLS * 4, 256,  0, stream>>>(feat, label, counts, first, part, colsum);
    k_sweepf<4> <<<C_CLS,     1024, 0, stream>>>(part, colsum, counts, first, S, INVg, mu, rank_g, ld2);
  }
  k_pairs<<<dim3(C_CLS, C_CLS), 256, 0, stream>>>(S, INVg, mu, ld2, rank_g, out);
}

// Round 8
// 152.532 us; speedup vs baseline: 1.3235x; 1.0464x over previous
//
#include <hip/hip_runtime.h>

#define B_ROWS 16384
#define K_DIM  128
#define C_CLS  32

// ws layout (bytes) — no zero-init required anywhere (all partials non-atomic)
#define O_COUNTSP 0                // 256 int  (per-block counts)
#define O_FIRSTP  1024             // 256 int  (per-block first-row)
#define O_RANK    2048             // 32 int
#define O_LD2     2304             // 32 float
#define O_MU      2560             // 32*128*4 = 16 KiB
#define O_COLSUMP 20480            // 256*128*4 = 128 KiB (per-block colsums)
#define O_S       151552           // 2 MiB
#define O_PART    2248704          // NSPLIT*32 slabs * 64 KiB
// INV for class c aliases class c's OWN partial slab (part + c*NSPLIT*16384):
// block c reads its slabs at kernel start and writes INV at the end -> no
// cross-block overlap (r7's layout was only timing-safe; this is race-free).

// ---------------------------------------------------------------------------
// K2: per-class partial second moments, fully atomic-free. Block (c,s)
// ballot-compacts its label chunk into an LDS row list, 8x8-register-tile
// Gram over 32-row LDS-staged batches, then writes 64 KB Gram partial +
// 128-col colsum partial + count/first partial, all block-private.
// ---------------------------------------------------------------------------
template<int NSPLIT>
__global__ __launch_bounds__(256) void k_scatter(const float* __restrict__ feat,
    const int* __restrict__ label, int* __restrict__ counts_p,
    int* __restrict__ first_p, float* __restrict__ part,
    float* __restrict__ colsum_p) {
  constexpr int CH = B_ROWS / NSPLIT;
  const int bid = blockIdx.x;
  const int c = bid / NSPLIT, s = bid % NSPLIT;
  __shared__ int lls[CH];
  __shared__ int lcnt, lmin;
  __shared__ __align__(16) float ls[32 * 128];
  __shared__ float lcs[256];
  const int t = threadIdx.x;
  if (t == 0) { lcnt = 0; lmin = 0x7fffffff; }
  __syncthreads();
  // ---- compaction scan of this chunk ----
  int myMin = 0x7fffffff;
  const int lane = t & 63;
  for (int r0 = 0; r0 < CH; r0 += 256) {
    const int i = s * CH + r0 + t;
    const bool match = (label[i] == c);
    unsigned long long mask = __ballot(match);
    int prefix = __popcll(mask & ((1ull << lane) - 1ull));
    int wcnt = __popcll(mask);
    int base = 0;
    if (lane == 0 && wcnt) base = atomicAdd(&lcnt, wcnt);
    base = __shfl(base, 0);
    if (match) { lls[base + prefix] = i; myMin = min(myMin, i); }
  }
  #pragma unroll
  for (int off = 32; off > 0; off >>= 1) myMin = min(myMin, __shfl_xor(myMin, off));
  if (lane == 0) atomicMin(&lmin, myMin);   // LDS atomic, 4/block
  __syncthreads();
  const int n = lcnt;
  if (t == 0) { counts_p[bid] = n; first_p[bid] = lmin; }

  // ---- Gram accumulation ----
  const int tr = t >> 4, tc = t & 15;
  float acc[8][8];
  #pragma unroll
  for (int i = 0; i < 8; ++i)
    #pragma unroll
    for (int j = 0; j < 8; ++j) acc[i][j] = 0.f;
  float cs = 0.f;
  const int col = t & 127, half = t >> 7;
  for (int base2 = 0; base2 < n; base2 += 32) {
    const int nb = min(32, n - base2);
    __syncthreads();             // protect ls against previous-iter readers
    #pragma unroll
    for (int w = 0; w < 4; ++w) {
      int f4 = w * 256 + t;      // 0..1023 over 32 rows x 32 float4
      int r = f4 >> 5, c4 = f4 & 31;
      float4 v = make_float4(0.f, 0.f, 0.f, 0.f);
      if (r < nb) {
        int row = lls[base2 + r];
        v = ((const float4*)(feat + (long)row * K_DIM))[c4];
      }
      ((float4*)ls)[f4] = v;     // zero-padded tail rows contribute nothing
    }
    __syncthreads();
    #pragma unroll
    for (int r0 = 0; r0 < 16; ++r0) cs += ls[(half * 16 + r0) * 128 + col];
    for (int r = 0; r < nb; ++r) {
      const float4* lr = (const float4*)(ls + r * 128);
      float4 A0 = lr[tr * 2], A1 = lr[tr * 2 + 1];
      float4 B0 = lr[tc * 2], B1 = lr[tc * 2 + 1];
      float av[8] = {A0.x, A0.y, A0.z, A0.w, A1.x, A1.y, A1.z, A1.w};
      float bv[8] = {B0.x, B0.y, B0.z, B0.w, B1.x, B1.y, B1.z, B1.w};
      #pragma unroll
      for (int i = 0; i < 8; ++i)
        #pragma unroll
        for (int j = 0; j < 8; ++j) acc[i][j] += av[i] * bv[j];
    }
  }
  float* Pc = part + (long)bid * 16384;
  #pragma unroll
  for (int i = 0; i < 8; ++i) {
    float4* prow = (float4*)(Pc + (tr * 8 + i) * 128);
    prow[tc * 2]     = make_float4(acc[i][0], acc[i][1], acc[i][2], acc[i][3]);
    prow[tc * 2 + 1] = make_float4(acc[i][4], acc[i][5], acc[i][6], acc[i][7]);
  }
  lcs[t] = cs;
  __syncthreads();
  if (t < 128) colsum_p[bid * 128 + t] = lcs[t] + lcs[t + 128];
}

// ---------------------------------------------------------------------------
// K4: FUSED finalize + LOOKAHEAD sweep-operator inversion + log2-det.
// r8: r5/r7 both measured ~1030 cy/step independent of wave count -> the
// step cost is the serial chain export->barrier->read d->rcp->wc->update.
// Lookahead (LU-style): at step P, the owner half-wave of row P+1 computes
// its updated row as soon as wc is ready (an = A[qn] - vb[P+1]*wc — the
// identical expression bulk computes) and exports it with the parked-diag
// fixup into the other vbuf BEFORE the barrier. Step P+1 starts with its
// pivot row already in LDS; the export/read round-trip hides under bulk FMA.
// One barrier per step; buffer-parity safety unchanged (step P's lookahead
// writes buf[(P+1)&1], whose last readers were step P-1, separated by the
// barrier at the end of step P-1).
//
// Parked-diag trick (r5-verified): exported row P carries d-1 at slot P and
// raw d at slot 128; the generic update is then exact for row and col P;
// only diag [P][P] is off by exactly +2 (introduced once, additive, never
// re-read) -> fixed in the final write INV = -A + 2*[diag].
// ---------------------------------------------------------------------------
template<int NSPLIT>
__global__ __launch_bounds__(1024) void k_sweepf(float* __restrict__ part,
    const float* __restrict__ colsum_p, const int* __restrict__ counts_p,
    const int* __restrict__ first_p, float* __restrict__ S,
    float* __restrict__ mu, int* __restrict__ rank_g, float* __restrict__ ld2,
    float* __restrict__ out) {
  const int c = blockIdx.x, t = threadIdx.x;
  __shared__ __align__(16) float ml[128];
  __shared__ __align__(16) float vbuf[2][132];   // slot [128] carries d
  __shared__ int lfirst[C_CLS];
  if (c == 0 && t == 0) out[0] = 0.f;            // k_pairs accumulates later
  int n = 0;
  #pragma unroll
  for (int k = 0; k < NSPLIT; ++k) n += counts_p[c * NSPLIT + k];
  const float rn = 1.0f / (float)n;
  if (t < 128) {
    float m = 0.f;
    #pragma unroll
    for (int k = 0; k < NSPLIT; ++k) m += colsum_p[(c * NSPLIT + k) * 128 + t];
    m *= rn;
    ml[t] = m;
    mu[c * 128 + t] = m;
  }
  if (t < C_CLS) {
    int f = 0x7fffffff;
    #pragma unroll
    for (int k = 0; k < NSPLIT; ++k) f = min(f, first_p[t * NSPLIT + k]);
    lfirst[t] = f;
  }
  __syncthreads();
  if (t == 0) {
    const int f = lfirst[c];
    int r = 0;
    for (int c2 = 0; c2 < C_CLS; ++c2)
      r += (lfirst[c2] < f) || (lfirst[c2] == f && c2 < c);
    rank_g[c] = r;
  }
  // ---- inline finalize: A = (sum partials)*rn - mu mu^T + I ; write S ----
  const int h = t >> 5, c4i = t & 31;            // row rq = 32q+h, f4col c4i
  float4 A[4];
  float4* S4 = (float4*)(S + c * 16384);
  #pragma unroll
  for (int q = 0; q < 4; ++q) {
    const int f4 = q * 1024 + t;
    float4 v = make_float4(0.f, 0.f, 0.f, 0.f);
    #pragma unroll
    for (int k = 0; k < NSPLIT; ++k) {
      const float4 p = ((const float4*)(part + (long)(c * NSPLIT + k) * 16384))[f4];
      v.x += p.x; v.y += p.y; v.z += p.z; v.w += p.w;
    }
    const int row = q * 32 + h;
    const float mr = ml[row];
    const float4 mc = ((const float4*)ml)[c4i];
    const int b = 4 * c4i;
    v.x = v.x * rn - mr * mc.x + ((row == b + 0) ? 1.f : 0.f);
    v.y = v.y * rn - mr * mc.y + ((row == b + 1) ? 1.f : 0.f);
    v.z = v.z * rn - mr * mc.z + ((row == b + 2) ? 1.f : 0.f);
    v.w = v.w * rn - mr * mc.w + ((row == b + 3) ? 1.f : 0.f);
    A[q] = v;
    S4[f4] = v;
  }
  // ---- prologue: export row 0 (owners h==0, q=0) with fixup ----
  if (h == 0) {
    float4 ex = A[0];
    if (c4i == 0) { vbuf[0][128] = ex.x; ex.x -= 1.f; }
    ((float4*)vbuf[0])[c4i] = ex;
  }
  __syncthreads();
  float lda = 0.f;
  for (int P = 0; P < 128; ++P) {
    const float* vb = vbuf[P & 1];
    float* vbn = vbuf[(P + 1) & 1];
    const float d = vb[128];
    const float dinv = 1.0f / d;
    lda += __log2f(d);
    const float4 vc = ((const float4*)vb)[c4i];
    const float4 wc = make_float4(vc.x * dinv, vc.y * dinv, vc.z * dinv, vc.w * dinv);
    // ---- lookahead: owner of row P+1 updates+exports it NOW ----
    if (P < 127 && h == ((P + 1) & 31)) {
      const int qn = (P + 1) >> 5;
      const float vrn = vb[P + 1];
      float4 aq = A[0];
      #pragma unroll
      for (int q = 1; q < 4; ++q) if (q == qn) aq = A[q];   // static select
      float4 ex;
      ex.x = aq.x - vrn * wc.x;
      ex.y = aq.y - vrn * wc.y;
      ex.z = aq.z - vrn * wc.z;
      ex.w = aq.w - vrn * wc.w;
      if (c4i == ((P + 1) >> 2)) {             // float4 holding diag of row P+1
        const int e = (P + 1) & 3;
        const float dv = (e == 0) ? ex.x : (e == 1) ? ex.y : (e == 2) ? ex.z : ex.w;
        vbn[128] = dv;                          // broadcast raw d
        if (e == 0) ex.x -= 1.f; else if (e == 1) ex.y -= 1.f;
        else if (e == 2) ex.z -= 1.f; else ex.w -= 1.f;      // slot P+1 = d-1
      }
      ((float4*)vbn)[c4i] = ex;
    }
    // ---- bulk rank-1 update (also produces the same an for row P+1) ----
    #pragma unroll
    for (int q = 0; q < 4; ++q) {
      const float vr = vb[q * 32 + h];         // symmetric: col-P val by row idx
      A[q].x -= vr * wc.x;
      A[q].y -= vr * wc.y;
      A[q].z -= vr * wc.z;
      A[q].w -= vr * wc.w;
    }
    __syncthreads();
  }
  // ---- INV = -A + 2*[diag], into class c's OWN first partial slab ----
  float4* O4 = (float4*)(part + (long)c * NSPLIT * 16384);
  const int e = h & 3;                          // diag element position = rq & 3
  #pragma unroll
  for (int q = 0; q < 4; ++q) {
    const int rq = q * 32 + h;
    const float pf = (c4i == (rq >> 2)) ? 2.f : 0.f;
    float4 o;
    o.x = ((e == 0) ? pf : 0.f) - A[q].x;
    o.y = ((e == 1) ? pf : 0.f) - A[q].y;
    o.z = ((e == 2) ? pf : 0.f) - A[q].z;
    o.w = ((e == 3) ? pf : 0.f) - A[q].w;
    O4[q * 1024 + t] = o;
  }
  if (t == 0) ld2[c] = lda;            // v_log_f32 is log2 = slogdet/ln2
}

// ---------------------------------------------------------------------------
// K5: pairwise tr+quad fused + (block 0,0) the -sum(mu^2) term; accumulates
// straight into d_out (zeroed by k_sweepf). kl = 0.5*(ld2j-ld2i-128+sum).
// INV is read from the partial region at stride invStride floats.
// ---------------------------------------------------------------------------
__global__ __launch_bounds__(256) void k_pairs(const float* __restrict__ S,
    const float* __restrict__ INVg, const long invStride,
    const float* __restrict__ mu, const float* __restrict__ ld2,
    const int* __restrict__ rank_g, float* __restrict__ out) {
  const int j = blockIdx.x, i = blockIdx.y;
  const int t = threadIdx.x;
  __shared__ __align__(16) float dl[128];
  __shared__ float wsum[4];
  if (i == 0 && j == 0) {              // block-uniform: fused -sum(mu^2)
    float s2 = 0.f;
    #pragma unroll
    for (int q = 0; q < 16; ++q) { float m = mu[q * 256 + t]; s2 += m * m; }
    #pragma unroll
    for (int off = 32; off > 0; off >>= 1) s2 += __shfl_xor(s2, off);
    if ((t & 63) == 0) wsum[t >> 6] = s2;
    __syncthreads();
    if (t == 0) atomicAdd(out, -(wsum[0] + wsum[1] + wsum[2] + wsum[3]));
    __syncthreads();                   // wsum reused below
  }
  if (rank_g[i] > C_CLS - 2 || rank_g[j] < 1) return;   // block-uniform
  if (t < 128) dl[t] = mu[i * 128 + t] - mu[j * 128 + t];
  __syncthreads();
  const float4* Si4 = (const float4*)(S + i * 16384);
  const float4* Ij4 = (const float4*)(INVg + (long)j * invStride);
  float s = 0.f;
  #pragma unroll
  for (int q = 0; q < 16; ++q) {
    int f4 = q * 256 + t;
    int a = f4 >> 5, b4 = f4 & 31;
    float da = dl[a];
    float4 db = ((const float4*)dl)[b4];
    float4 si = Si4[f4], ij = Ij4[f4];
    s += ij.x * (si.x + da * db.x);
    s += ij.y * (si.y + da * db.y);
    s += ij.z * (si.z + da * db.z);
    s += ij.w * (si.w + da * db.w);
  }
  #pragma unroll
  for (int off = 32; off > 0; off >>= 1) s += __shfl_xor(s, off);
  if ((t & 63) == 0) wsum[t >> 6] = s;
  __syncthreads();
  if (t == 0) {
    float tot = wsum[0] + wsum[1] + wsum[2] + wsum[3];
    float kl = 0.5f * ((ld2[j] - ld2[i]) - 128.0f + tot);
    atomicAdd(out, kl);
  }
}

extern "C" void kernel_launch(void* const* d_in, const int* in_sizes, int n_in,
                              void* d_out, int out_size, void* d_ws, size_t ws_size,
                              hipStream_t stream) {
  const float* feat  = (const float*)d_in[0];
  const int*   label = (const int*)d_in[1];
  // d_in[2] (pan) is unused by the reference module.
  float* out = (float*)d_out;
  char*  ws  = (char*)d_ws;

  int*   counts_p = (int*)(ws + O_COUNTSP);
  int*   first_p  = (int*)(ws + O_FIRSTP);
  int*   rank_g   = (int*)(ws + O_RANK);
  float* ld2      = (float*)(ws + O_LD2);
  float* mu       = (float*)(ws + O_MU);
  float* colsum_p = (float*)(ws + O_COLSUMP);
  float* S        = (float*)(ws + O_S);
  float* part     = (float*)(ws + O_PART);

  const size_t need8 = (size_t)O_PART + (size_t)C_CLS * 8 * 65536;

  if (ws_size >= need8) {
    k_scatter<8><<<C_CLS * 8, 256,  0, stream>>>(feat, label, counts_p, first_p, part, colsum_p);
    k_sweepf<8> <<<C_CLS,     1024, 0, stream>>>(part, colsum_p, counts_p, first_p, S, mu, rank_g, ld2, out);
    k_pairs     <<<dim3(C_CLS, C_CLS), 256, 0, stream>>>(S, part, (long)8 * 16384, mu, ld2, rank_g, out);
  } else {
    k_scatter<4><<<C_CLS * 4, 256,  0, stream>>>(feat, label, counts_p, first_p, part, colsum_p);
    k_sweepf<4> <<<C_CLS,     1024, 0, stream>>>(part, colsum_p, counts_p, first_p, S, mu, rank_g, ld2, out);
    k_pairs     <<<dim3(C_CLS, C_CLS), 256, 0, stream>>>(S, part, (long)4 * 16384, mu, ld2, rank_g, out);
  }
}